// Round 1
// baseline (4347.905 us; speedup 1.0000x reference)
//
#include <hip/hip_runtime.h>
#include <hip/hip_bf16.h>
#include <math.h>

#define B_ 2
#define T_ 512
#define D_ 256
#define NH_ 4
#define NI_ 4096
#define IN_DIM_ 372
#define NL_ 6
#define EPS_ 1e-5f

#define BM 64
#define BN 64
#define BK 16

// ---------- block-wide sum over 256 threads (4 waves) ----------
__device__ __forceinline__ float blkSum256(float v, float* sb4) {
  #pragma unroll
  for (int o = 32; o > 0; o >>= 1) v += __shfl_down(v, o, 64);
  int w = threadIdx.x >> 6;
  __syncthreads();                    // protect sb4 reuse across calls
  if ((threadIdx.x & 63) == 0) sb4[w] = v;
  __syncthreads();
  return sb4[0] + sb4[1] + sb4[2] + sb4[3];
}

// ---------- rope cos/sin tables: [T][NI/2] ----------
__global__ __launch_bounds__(256)
void k_rope_tables(float* __restrict__ cosT, float* __restrict__ sinT) {
  int idx = blockIdx.x * 256 + threadIdx.x;
  if (idx >= T_ * (NI_ / 2)) return;
  int t = idx >> 11;          // /2048
  int k = idx & 2047;
  float freq = exp2f(-(float)k * (1.0f / 128.0f));   // theta=2^16, NI=4096 -> 2^(-k/128)
  float ph = (float)t * freq;
  cosT[idx] = cosf(ph);
  sinT[idx] = sinf(ph);
}

// ---------- input projection + LN: h[bt,d] = LN(x[bt,:] @ in_W + in_b) ----------
__global__ __launch_bounds__(256)
void k_input(const float* __restrict__ x, const float* __restrict__ W,
             const float* __restrict__ b, float* __restrict__ h) {
  __shared__ float xr[IN_DIM_];
  __shared__ float sb[4];
  int bt = blockIdx.x;
  int d  = threadIdx.x;
  const float* xrow = x + (long)bt * IN_DIM_;
  for (int k = d; k < IN_DIM_; k += 256) xr[k] = xrow[k];
  __syncthreads();
  float acc = b[d];
  for (int k = 0; k < IN_DIM_; k++) acc += xr[k] * W[k * D_ + d];
  float mean = blkSum256(acc, sb) * (1.0f / D_);
  float c = acc - mean;
  float var = blkSum256(c * c, sb) * (1.0f / D_);
  h[(long)bt * D_ + d] = c * rsqrtf(var + EPS_);
}

// ---------- h_sparse = relu(h @ encoder[head]); qr = rope(h_sparse) ----------
// grid: (NI/64, (B*T)/64, NH)
__global__ __launch_bounds__(256)
void k_enc(const float* __restrict__ h, const float* __restrict__ enc,
           const float* __restrict__ cosT, const float* __restrict__ sinT,
           float* __restrict__ hs, float* __restrict__ qr) {
  __shared__ float As[BK][BM];
  __shared__ float Bs[BK][BN];
  int head = blockIdx.z;
  int row0 = blockIdx.y * BM;
  int col0 = blockIdx.x * BN;
  const float* Bp = enc + (long)head * D_ * NI_;
  int tid = threadIdx.x;
  int tx = tid & 15, ty = tid >> 4;
  float acc[4][4] = {};
  for (int k0 = 0; k0 < D_; k0 += BK) {
    {
      int m = tid >> 2, kk = (tid & 3) * 4;
      const float4 a = *(const float4*)(h + (long)(row0 + m) * D_ + k0 + kk);
      As[kk + 0][m] = a.x; As[kk + 1][m] = a.y; As[kk + 2][m] = a.z; As[kk + 3][m] = a.w;
    }
    {
      int kr = tid >> 4, n4 = (tid & 15) * 4;
      *(float4*)&Bs[kr][n4] = *(const float4*)(Bp + (long)(k0 + kr) * NI_ + col0 + n4);
    }
    __syncthreads();
    #pragma unroll
    for (int kk = 0; kk < BK; kk++) {
      float a[4], bb[4];
      #pragma unroll
      for (int i = 0; i < 4; i++) a[i] = As[kk][ty * 4 + i];
      #pragma unroll
      for (int j = 0; j < 4; j++) bb[j] = Bs[kk][tx * 4 + j];
      #pragma unroll
      for (int i = 0; i < 4; i++)
        #pragma unroll
        for (int j = 0; j < 4; j++) acc[i][j] += a[i] * bb[j];
    }
    __syncthreads();
  }
  #pragma unroll
  for (int i = 0; i < 4; i++) {
    int r = row0 + ty * 4 + i;
    int b = r >> 9, t = r & 511;
    long orow = ((long)(b * NH_ + head) * T_ + t) * (long)NI_;
    const float* cR = cosT + (long)t * (NI_ / 2);
    const float* sR = sinT + (long)t * (NI_ / 2);
    int n0 = col0 + tx * 4;
    float v0 = fmaxf(acc[i][0], 0.f), v1 = fmaxf(acc[i][1], 0.f);
    float v2 = fmaxf(acc[i][2], 0.f), v3 = fmaxf(acc[i][3], 0.f);
    *(float4*)(hs + orow + n0) = make_float4(v0, v1, v2, v3);
    float c0 = cR[n0 >> 1], s0 = sR[n0 >> 1];
    float c1 = cR[(n0 >> 1) + 1], s1 = sR[(n0 >> 1) + 1];
    float q0 = v0 * c0 - v1 * s0;
    float q1 = v0 * s0 + v1 * c0;
    float q2 = v2 * c1 - v3 * s1;
    float q3 = v2 * s1 + v3 * c1;
    *(float4*)(qr + orow + n0) = make_float4(q0, q1, q2, q3);
  }
}

// ---------- scores = qr @ qr^T per (b,h) ----------
// grid: (T/64, T/64, B*NH)
__global__ __launch_bounds__(256)
void k_scores(const float* __restrict__ qr, float* __restrict__ sc) {
  __shared__ float As[BK][BM];
  __shared__ float Bs[BK][BN];
  int z = blockIdx.z;
  const float* A = qr + (long)z * T_ * NI_;
  float* C = sc + (long)z * T_ * T_;
  int row0 = blockIdx.y * BM;
  int col0 = blockIdx.x * BN;
  int tid = threadIdx.x;
  int tx = tid & 15, ty = tid >> 4;
  float acc[4][4] = {};
  for (int k0 = 0; k0 < NI_; k0 += BK) {
    {
      int m = tid >> 2, kk = (tid & 3) * 4;
      const float4 a = *(const float4*)(A + (long)(row0 + m) * NI_ + k0 + kk);
      As[kk + 0][m] = a.x; As[kk + 1][m] = a.y; As[kk + 2][m] = a.z; As[kk + 3][m] = a.w;
      const float4 bq = *(const float4*)(A + (long)(col0 + m) * NI_ + k0 + kk);
      Bs[kk + 0][m] = bq.x; Bs[kk + 1][m] = bq.y; Bs[kk + 2][m] = bq.z; Bs[kk + 3][m] = bq.w;
    }
    __syncthreads();
    #pragma unroll
    for (int kk = 0; kk < BK; kk++) {
      float a[4], bb[4];
      #pragma unroll
      for (int i = 0; i < 4; i++) a[i] = As[kk][ty * 4 + i];
      #pragma unroll
      for (int j = 0; j < 4; j++) bb[j] = Bs[kk][tx * 4 + j];
      #pragma unroll
      for (int i = 0; i < 4; i++)
        #pragma unroll
        for (int j = 0; j < 4; j++) acc[i][j] += a[i] * bb[j];
    }
    __syncthreads();
  }
  #pragma unroll
  for (int i = 0; i < 4; i++) {
    int r = row0 + ty * 4 + i;
    *(float4*)(C + (long)r * T_ + col0 + tx * 4) =
        make_float4(acc[i][0], acc[i][1], acc[i][2], acc[i][3]);
  }
}

// ---------- yKV = LN(scores @ h_b) ----------
// grid: B*NH*T blocks, 256 threads (thread = d)
__global__ __launch_bounds__(256)
void k_ykv(const float* __restrict__ sc, const float* __restrict__ h,
           float* __restrict__ ykv) {
  __shared__ float srow[T_];
  __shared__ float sb[4];
  int blk = blockIdx.x;
  int t = blk & 511;
  int z = blk >> 9;          // b*NH + head
  int b = z >> 2;
  const float* scr = sc + ((long)z * T_ + t) * T_;
  int d = threadIdx.x;
  for (int s = d; s < T_; s += 256) srow[s] = scr[s];
  __syncthreads();
  const float* hb = h + (long)b * T_ * D_;
  float acc = 0.f;
  #pragma unroll 4
  for (int s = 0; s < T_; s++) acc += srow[s] * hb[(long)s * D_ + d];
  float mean = blkSum256(acc, sb) * (1.0f / D_);
  float c = acc - mean;
  float var = blkSum256(c * c, sb) * (1.0f / D_);
  ykv[(long)blk * D_ + d] = c * rsqrtf(var + EPS_);
}

// ---------- xy = relu(yKV @ encoder_v[head]) * h_sparse ----------
// grid: (NI/64, T/64, B*NH)
__global__ __launch_bounds__(256)
void k_ysp(const float* __restrict__ ykv, const float* __restrict__ encv,
           const float* __restrict__ hs, float* __restrict__ xy) {
  __shared__ float As[BK][BM];
  __shared__ float Bs[BK][BN];
  int z = blockIdx.z;
  int head = z & 3;
  int row0 = blockIdx.y * BM;
  int col0 = blockIdx.x * BN;
  const float* A = ykv + (long)z * T_ * D_;
  const float* Bp = encv + (long)head * D_ * NI_;
  int tid = threadIdx.x;
  int tx = tid & 15, ty = tid >> 4;
  float acc[4][4] = {};
  for (int k0 = 0; k0 < D_; k0 += BK) {
    {
      int m = tid >> 2, kk = (tid & 3) * 4;
      const float4 a = *(const float4*)(A + (long)(row0 + m) * D_ + k0 + kk);
      As[kk + 0][m] = a.x; As[kk + 1][m] = a.y; As[kk + 2][m] = a.z; As[kk + 3][m] = a.w;
    }
    {
      int kr = tid >> 4, n4 = (tid & 15) * 4;
      *(float4*)&Bs[kr][n4] = *(const float4*)(Bp + (long)(k0 + kr) * NI_ + col0 + n4);
    }
    __syncthreads();
    #pragma unroll
    for (int kk = 0; kk < BK; kk++) {
      float a[4], bb[4];
      #pragma unroll
      for (int i = 0; i < 4; i++) a[i] = As[kk][ty * 4 + i];
      #pragma unroll
      for (int j = 0; j < 4; j++) bb[j] = Bs[kk][tx * 4 + j];
      #pragma unroll
      for (int i = 0; i < 4; i++)
        #pragma unroll
        for (int j = 0; j < 4; j++) acc[i][j] += a[i] * bb[j];
    }
    __syncthreads();
  }
  #pragma unroll
  for (int i = 0; i < 4; i++) {
    int r = row0 + ty * 4 + i;
    long off = ((long)z * T_ + r) * (long)NI_ + col0 + tx * 4;
    float4 hv = *(const float4*)(hs + off);
    float4 o;
    o.x = fmaxf(acc[i][0], 0.f) * hv.x;
    o.y = fmaxf(acc[i][1], 0.f) * hv.y;
    o.z = fmaxf(acc[i][2], 0.f) * hv.z;
    o.w = fmaxf(acc[i][3], 0.f) * hv.w;
    *(float4*)(xy + off) = o;
  }
}

// ---------- yMLP partials: ymlpp[z] = xy[b,h] @ dec[h]  (K split 4 ways) ----------
// grid: (D/64, T/64, B*NH*4); z = ((b*4+h)*4+ks)
__global__ __launch_bounds__(256)
void k_ymlp(const float* __restrict__ xy, const float* __restrict__ dec,
            float* __restrict__ ymlpp) {
  __shared__ float As[BK][BM];
  __shared__ float Bs[BK][BN];
  int z = blockIdx.z;
  int b = z >> 4;
  int head = (z >> 2) & 3;
  int ks = z & 3;
  int row0 = blockIdx.y * BM;
  int col0 = blockIdx.x * BN;
  const float* A = xy + ((long)(b * NH_ + head) * T_) * (long)NI_;
  const float* Bp = dec + (long)head * NI_ * D_;
  int tid = threadIdx.x;
  int tx = tid & 15, ty = tid >> 4;
  float acc[4][4] = {};
  int kbeg = ks * (NI_ / 4), kend = kbeg + (NI_ / 4);
  for (int k0 = kbeg; k0 < kend; k0 += BK) {
    {
      int m = tid >> 2, kk = (tid & 3) * 4;
      const float4 a = *(const float4*)(A + (long)(row0 + m) * NI_ + k0 + kk);
      As[kk + 0][m] = a.x; As[kk + 1][m] = a.y; As[kk + 2][m] = a.z; As[kk + 3][m] = a.w;
    }
    {
      int kr = tid >> 4, n4 = (tid & 15) * 4;
      *(float4*)&Bs[kr][n4] = *(const float4*)(Bp + (long)(k0 + kr) * D_ + col0 + n4);
    }
    __syncthreads();
    #pragma unroll
    for (int kk = 0; kk < BK; kk++) {
      float a[4], bb[4];
      #pragma unroll
      for (int i = 0; i < 4; i++) a[i] = As[kk][ty * 4 + i];
      #pragma unroll
      for (int j = 0; j < 4; j++) bb[j] = Bs[kk][tx * 4 + j];
      #pragma unroll
      for (int i = 0; i < 4; i++)
        #pragma unroll
        for (int j = 0; j < 4; j++) acc[i][j] += a[i] * bb[j];
    }
    __syncthreads();
  }
  #pragma unroll
  for (int i = 0; i < 4; i++) {
    int r = row0 + ty * 4 + i;
    *(float4*)(ymlpp + ((long)z * T_ + r) * D_ + col0 + tx * 4) =
        make_float4(acc[i][0], acc[i][1], acc[i][2], acc[i][3]);
  }
}

// ---------- h = LN(h + LN(sum of 16 yMLP partials)) ----------
__global__ __launch_bounds__(256)
void k_dln(const float* __restrict__ ymlpp, float* __restrict__ h) {
  __shared__ float sb[4];
  int bt = blockIdx.x;
  int b = bt >> 9, t = bt & 511;
  int d = threadIdx.x;
  float acc = 0.f;
  #pragma unroll
  for (int p = 0; p < 16; p++)
    acc += ymlpp[(((long)(b * 16 + p)) * T_ + t) * D_ + d];
  float mean = blkSum256(acc, sb) * (1.0f / D_);
  float c = acc - mean;
  float var = blkSum256(c * c, sb) * (1.0f / D_);
  float u = c * rsqrtf(var + EPS_);
  float v2 = h[(long)bt * D_ + d] + u;
  float m2 = blkSum256(v2, sb) * (1.0f / D_);
  float c2 = v2 - m2;
  float va2 = blkSum256(c2 * c2, sb) * (1.0f / D_);
  h[(long)bt * D_ + d] = c2 * rsqrtf(va2 + EPS_);
}

// ---------- head: out[bt,j] = h[bt,:] @ head_W[:,j] + head_b[j] ----------
__global__ __launch_bounds__(384)
void k_head(const float* __restrict__ h, const float* __restrict__ W,
            const float* __restrict__ bb, float* __restrict__ out) {
  __shared__ float hr[D_];
  int bt = blockIdx.x;
  int j = threadIdx.x;
  for (int k = j; k < D_; k += 384) hr[k] = h[(long)bt * D_ + k];
  __syncthreads();
  if (j < IN_DIM_) {
    float acc = bb[j];
    for (int d2 = 0; d2 < D_; d2++) acc += hr[d2] * W[(long)d2 * IN_DIM_ + j];
    out[(long)bt * IN_DIM_ + j] = acc;
  }
}

extern "C" void kernel_launch(void* const* d_in, const int* in_sizes, int n_in,
                              void* d_out, int out_size, void* d_ws, size_t ws_size,
                              hipStream_t stream) {
  const float* x    = (const float*)d_in[0];
  const float* in_W = (const float*)d_in[1];
  const float* in_b = (const float*)d_in[2];
  const float* enc  = (const float*)d_in[3];
  const float* encv = (const float*)d_in[4];
  const float* dec  = (const float*)d_in[5];
  const float* hW   = (const float*)d_in[6];
  const float* hb   = (const float*)d_in[7];
  float* out = (float*)d_out;
  float* ws  = (float*)d_ws;

  size_t off = 0;
  float* cosT  = ws + off; off += (size_t)T_ * (NI_ / 2);        // 1 Mi
  float* sinT  = ws + off; off += (size_t)T_ * (NI_ / 2);        // 1 Mi
  float* h     = ws + off; off += (size_t)B_ * T_ * D_;          // 256 Ki
  float* hs    = ws + off; off += (size_t)B_ * NH_ * T_ * NI_;   // 16 Mi
  float* qr    = ws + off; off += (size_t)B_ * NH_ * T_ * NI_;   // 16 Mi (reused as xy)
  float* sc    = ws + off; off += (size_t)B_ * NH_ * T_ * T_;    // 2 Mi
  float* ykv   = ws + off; off += (size_t)B_ * NH_ * T_ * D_;    // 1 Mi
  float* ymlpp = ws + off; off += (size_t)32 * T_ * D_;          // 4 Mi

  k_rope_tables<<<dim3((T_ * (NI_ / 2) + 255) / 256), dim3(256), 0, stream>>>(cosT, sinT);
  k_input<<<dim3(B_ * T_), dim3(256), 0, stream>>>(x, in_W, in_b, h);

  for (int l = 0; l < NL_; l++) {
    k_enc<<<dim3(NI_ / BN, (B_ * T_) / BM, NH_), dim3(256), 0, stream>>>(
        h, enc, cosT, sinT, hs, qr);
    k_scores<<<dim3(T_ / BN, T_ / BM, B_ * NH_), dim3(256), 0, stream>>>(qr, sc);
    k_ykv<<<dim3(B_ * NH_ * T_), dim3(256), 0, stream>>>(sc, h, ykv);
    k_ysp<<<dim3(NI_ / BN, T_ / BM, B_ * NH_), dim3(256), 0, stream>>>(ykv, encv, hs, qr);
    k_ymlp<<<dim3(D_ / BN, T_ / BM, B_ * NH_ * 4), dim3(256), 0, stream>>>(qr, dec, ymlpp);
    k_dln<<<dim3(B_ * T_), dim3(256), 0, stream>>>(ymlpp, h);
  }

  k_head<<<dim3(B_ * T_), dim3(384), 0, stream>>>(h, hW, hb, out);
}

// Round 2
// 1150.054 us; speedup vs baseline: 3.7806x; 3.7806x over previous
//
#include <hip/hip_runtime.h>
#include <math.h>

#define B_ 2
#define T_ 512
#define D_ 256
#define NH_ 4
#define NI_ 4096
#define IN_DIM_ 372
#define NL_ 6
#define EPS_ 1e-5f

typedef unsigned short u16;
typedef __attribute__((ext_vector_type(4))) float f32x4;
typedef __attribute__((ext_vector_type(8))) short bf16x8;

__device__ __forceinline__ u16 f2b(float f) {
  union { float f; unsigned u; } v; v.f = f;
  unsigned r = v.u + 0x7fffu + ((v.u >> 16) & 1u);
  return (u16)(r >> 16);
}
__device__ __forceinline__ float b2f(u16 s) {
  union { unsigned u; float f; } v; v.u = ((unsigned)s) << 16;
  return v.f;
}

__device__ __forceinline__ void gload16(const u16* g, u16* l) {
  __builtin_amdgcn_global_load_lds(
      (const __attribute__((address_space(1))) unsigned int*)g,
      (__attribute__((address_space(3))) unsigned int*)l, 16, 0, 0);
}

// ---------- block-wide sum over 256 threads (4 waves) ----------
__device__ __forceinline__ float blkSum256(float v, float* sb4) {
  #pragma unroll
  for (int o = 32; o > 0; o >>= 1) v += __shfl_down(v, o, 64);
  int w = threadIdx.x >> 6;
  __syncthreads();
  if ((threadIdx.x & 63) == 0) sb4[w] = v;
  __syncthreads();
  return sb4[0] + sb4[1] + sb4[2] + sb4[3];
}

// ================= MFMA 128x128 tile GEMM core =================
// A: [M][K] bf16 row-major (lda = K). Bt: [N][K] bf16 row-major (same lda).
// Computes C tile [row0:+128][col0:+128] over K range [k0,k1), acc fp32.
__device__ __forceinline__ void gemm128(const u16* __restrict__ A,
                                        const u16* __restrict__ Bt,
                                        int lda, int k0, int k1,
                                        int row0, int col0,
                                        u16* Als, u16* Bls,
                                        f32x4 acc[4][4]) {
  const int tid = threadIdx.x;
  const int lane = tid & 63;
  const int wv = tid >> 6;
  const int wr = (wv >> 1) << 6;          // wave row offset: 0/64
  const int wc = (wv & 1) << 6;           // wave col offset: 0/64
  const int frow = lane & 15;
  const int kch = (lane >> 4) << 3;       // 0,8,16,24
  #pragma unroll
  for (int m = 0; m < 4; m++)
    #pragma unroll
    for (int n = 0; n < 4; n++) {
      f32x4 z = {0.f, 0.f, 0.f, 0.f};
      acc[m][n] = z;
    }
  for (int k = k0; k < k1; k += 32) {
    #pragma unroll
    for (int i = 0; i < 2; i++) {
      int s = tid + (i << 8);             // 512 slots of 8 bf16
      int r = s >> 2, c = (s & 3) << 3;
      gload16(A + (long)(row0 + r) * lda + k + c, Als + s * 8);
      gload16(Bt + (long)(col0 + r) * lda + k + c, Bls + s * 8);
    }
    __syncthreads();
    bf16x8 af[4], bfv[4];
    #pragma unroll
    for (int m = 0; m < 4; m++)
      af[m] = *(const bf16x8*)(Als + (wr + m * 16 + frow) * 32 + kch);
    #pragma unroll
    for (int n = 0; n < 4; n++)
      bfv[n] = *(const bf16x8*)(Bls + (wc + n * 16 + frow) * 32 + kch);
    #pragma unroll
    for (int m = 0; m < 4; m++)
      #pragma unroll
      for (int n = 0; n < 4; n++)
        acc[m][n] = __builtin_amdgcn_mfma_f32_16x16x32_bf16(af[m], bfv[n], acc[m][n], 0, 0, 0);
    __syncthreads();
  }
}

// C/D frag mapping: col = lane&15, row = (lane>>4)*4 + r   [m89 verified]
#define EPILOG_SETUP \
  const int lane = threadIdx.x & 63; \
  const int wv = threadIdx.x >> 6; \
  const int wr = (wv >> 1) << 6, wc = (wv & 1) << 6;

// ---------- rope tables: [T][NI/2] fp32 ----------
__global__ __launch_bounds__(256)
void k_rope_tables(float* __restrict__ cosT, float* __restrict__ sinT) {
  int idx = blockIdx.x * 256 + threadIdx.x;
  if (idx >= T_ * (NI_ / 2)) return;
  int t = idx >> 11;
  int k = idx & 2047;
  float freq = exp2f(-(float)k * (1.0f / 128.0f));
  float ph = (float)t * freq;
  cosT[idx] = cosf(ph);
  sinT[idx] = sinf(ph);
}

// ---------- transpose + fp32->bf16: dst[C][R] = bf16(src[R][C]), batch z ----------
__global__ __launch_bounds__(256)
void ktr(const float* __restrict__ src, u16* __restrict__ dst, int R, int C) {
  __shared__ float tile[64][65];
  long zoff = (long)blockIdx.z * R * C;
  int r0 = blockIdx.y * 64, c0 = blockIdx.x * 64;
  int tid = threadIdx.x;
  int tr = tid >> 4, tc4 = (tid & 15) * 4;
  #pragma unroll
  for (int i = 0; i < 4; i++) {
    int r = tr + i * 16;
    f32x4 v = *(const f32x4*)(src + zoff + (long)(r0 + r) * C + c0 + tc4);
    tile[r][tc4 + 0] = v.x; tile[r][tc4 + 1] = v.y;
    tile[r][tc4 + 2] = v.z; tile[r][tc4 + 3] = v.w;
  }
  __syncthreads();
  #pragma unroll
  for (int i = 0; i < 4; i++) {
    int c = tr + i * 16;
    ushort4 o;
    o.x = f2b(tile[tc4 + 0][c]); o.y = f2b(tile[tc4 + 1][c]);
    o.z = f2b(tile[tc4 + 2][c]); o.w = f2b(tile[tc4 + 3][c]);
    *(ushort4*)(dst + zoff + (long)(c0 + c) * R + r0 + tc4) = o;
  }
}

// ---------- input proj + LN; writes h_f32, h_bf, hT_bf ----------
__global__ __launch_bounds__(256)
void k_input(const float* __restrict__ x, const float* __restrict__ W,
             const float* __restrict__ b, float* __restrict__ hf,
             u16* __restrict__ hbf, u16* __restrict__ hT) {
  __shared__ float xr[IN_DIM_];
  __shared__ float sb[4];
  int bt = blockIdx.x;
  int d = threadIdx.x;
  const float* xrow = x + (long)bt * IN_DIM_;
  for (int k = d; k < IN_DIM_; k += 256) xr[k] = xrow[k];
  __syncthreads();
  float acc = b[d];
  for (int k = 0; k < IN_DIM_; k++) acc += xr[k] * W[k * D_ + d];
  float mean = blkSum256(acc, sb) * (1.0f / D_);
  float c = acc - mean;
  float var = blkSum256(c * c, sb) * (1.0f / D_);
  float out = c * rsqrtf(var + EPS_);
  hf[(long)bt * D_ + d] = out;
  hbf[(long)bt * D_ + d] = f2b(out);
  hT[((long)(bt >> 9) * D_ + d) * T_ + (bt & 511)] = f2b(out);
}

// ---------- h_sparse = relu(h@enc); hs + roped qr ----------
// grid (NI/128=32, BT/128=8, NH)
__global__ __launch_bounds__(256)
void g_enc(const u16* __restrict__ hbf, const u16* __restrict__ enct,
           const float* __restrict__ cosT, const float* __restrict__ sinT,
           u16* __restrict__ hs, u16* __restrict__ qr) {
  __shared__ u16 Als[128 * 32], Bls[128 * 32];
  int head = blockIdx.z;
  int row0 = blockIdx.y * 128, col0 = blockIdx.x * 128;
  f32x4 acc[4][4];
  gemm128(hbf, enct + (long)head * NI_ * D_, D_, 0, D_, row0, col0, Als, Bls, acc);
  EPILOG_SETUP
  #pragma unroll
  for (int m = 0; m < 4; m++) {
    #pragma unroll
    for (int n = 0; n < 4; n++) {
      int gc = col0 + wc + n * 16 + (lane & 15);
      bool ev = (gc & 1) == 0;
      int csi = gc >> 1;
      #pragma unroll
      for (int r = 0; r < 4; r++) {
        int gr = row0 + wr + m * 16 + ((lane >> 4) << 2) + r;  // b*512+t
        float v = fmaxf(acc[m][n][r], 0.f);
        float vo = __shfl_xor(v, 1, 64);
        if (ev) {
          int b = gr >> 9, t = gr & 511;
          float cc = cosT[t * (NI_ / 2) + csi], ss = sinT[t * (NI_ / 2) + csi];
          float q0 = v * cc - vo * ss;
          float q1 = v * ss + vo * cc;
          unsigned hw = (unsigned)f2b(v) | ((unsigned)f2b(vo) << 16);
          unsigned qw = (unsigned)f2b(q0) | ((unsigned)f2b(q1) << 16);
          long hsi = ((long)b * T_ + t) * (NH_ * NI_) + head * NI_ + gc;
          long qri = (((long)(b * NH_ + head)) * T_ + t) * NI_ + gc;
          *(unsigned*)(hs + hsi) = hw;
          *(unsigned*)(qr + qri) = qw;
        }
      }
    }
  }
}

// ---------- scores partials: scp[ks][z][t][s] = qr_slice @ qr_slice^T ----------
// grid (4, 4, 32): z2 = z*4+ks
__global__ __launch_bounds__(256)
void g_scores(const u16* __restrict__ qr, float* __restrict__ scp) {
  __shared__ u16 Als[128 * 32], Bls[128 * 32];
  int z2 = blockIdx.z;
  int z = z2 >> 2, ks = z2 & 3;
  const u16* A = qr + (long)z * T_ * NI_;
  int row0 = blockIdx.y * 128, col0 = blockIdx.x * 128;
  f32x4 acc[4][4];
  gemm128(A, A, NI_, ks * 1024, ks * 1024 + 1024, row0, col0, Als, Bls, acc);
  EPILOG_SETUP
  float* C = scp + ((long)(ks * 8 + z)) * T_ * T_;
  #pragma unroll
  for (int m = 0; m < 4; m++)
    #pragma unroll
    for (int n = 0; n < 4; n++) {
      int gc = col0 + wc + n * 16 + (lane & 15);
      #pragma unroll
      for (int r = 0; r < 4; r++) {
        int gr = row0 + wr + m * 16 + ((lane >> 4) << 2) + r;
        C[(long)gr * T_ + gc] = acc[m][n][r];
      }
    }
}

// ---------- reduce 4 score partials -> bf16 ----------
__global__ __launch_bounds__(256)
void k_scred(const float* __restrict__ scp, u16* __restrict__ scb) {
  const long SL = (long)8 * T_ * T_;
  long i = (long)blockIdx.x * 256 + threadIdx.x;   // over 2M/4
  f32x4 v = *(const f32x4*)(scp + i * 4);
  f32x4 v1 = *(const f32x4*)(scp + SL + i * 4);
  f32x4 v2 = *(const f32x4*)(scp + 2 * SL + i * 4);
  f32x4 v3 = *(const f32x4*)(scp + 3 * SL + i * 4);
  v = v + v1 + v2 + v3;
  ushort4 o;
  o.x = f2b(v.x); o.y = f2b(v.y); o.z = f2b(v.z); o.w = f2b(v.w);
  *(ushort4*)(scb + i * 4) = o;
}

// ---------- yKV partials: ykvp[ks][z][t][d] = scores@h ----------
// grid (2, 4, 32): z2 = z*4+ks
__global__ __launch_bounds__(256)
void g_ykv(const u16* __restrict__ scb, const u16* __restrict__ hT,
           float* __restrict__ ykvp) {
  __shared__ u16 Als[128 * 32], Bls[128 * 32];
  int z2 = blockIdx.z;
  int z = z2 >> 2, ks = z2 & 3;
  int b = z >> 2;
  const u16* A = scb + (long)z * T_ * T_;
  const u16* Bt = hT + (long)b * D_ * T_;
  int row0 = blockIdx.y * 128, col0 = blockIdx.x * 128;
  f32x4 acc[4][4];
  gemm128(A, Bt, T_, ks * 128, ks * 128 + 128, row0, col0, Als, Bls, acc);
  EPILOG_SETUP
  float* C = ykvp + ((long)(ks * 8 + z)) * T_ * D_;
  #pragma unroll
  for (int m = 0; m < 4; m++)
    #pragma unroll
    for (int n = 0; n < 4; n++) {
      int gc = col0 + wc + n * 16 + (lane & 15);
      #pragma unroll
      for (int r = 0; r < 4; r++) {
        int gr = row0 + wr + m * 16 + ((lane >> 4) << 2) + r;
        C[(long)gr * D_ + gc] = acc[m][n][r];
      }
    }
}

// ---------- sum 4 yKV partials + LN -> bf16 ----------
__global__ __launch_bounds__(256)
void k_lnykv(const float* __restrict__ ykvp, u16* __restrict__ ykvb) {
  __shared__ float sb[4];
  int blk = blockIdx.x;           // z*512 + t
  int d = threadIdx.x;
  const long SL = (long)8 * T_ * D_;
  long base = (long)blk * D_ + d;
  float acc = ykvp[base] + ykvp[SL + base] + ykvp[2 * SL + base] + ykvp[3 * SL + base];
  float mean = blkSum256(acc, sb) * (1.0f / D_);
  float c = acc - mean;
  float var = blkSum256(c * c, sb) * (1.0f / D_);
  ykvb[base] = f2b(c * rsqrtf(var + EPS_));
}

// ---------- xy = relu(yKV@encv) * hs ----------
// grid (32, 4, 8)
__global__ __launch_bounds__(256)
void g_ysp(const u16* __restrict__ ykvb, const u16* __restrict__ encvt,
           const u16* __restrict__ hs, u16* __restrict__ xy) {
  __shared__ u16 Als[128 * 32], Bls[128 * 32];
  int z = blockIdx.z;
  int b = z >> 2, head = z & 3;
  const u16* A = ykvb + (long)z * T_ * D_;
  int row0 = blockIdx.y * 128, col0 = blockIdx.x * 128;
  f32x4 acc[4][4];
  gemm128(A, encvt + (long)head * NI_ * D_, D_, 0, D_, row0, col0, Als, Bls, acc);
  EPILOG_SETUP
  #pragma unroll
  for (int m = 0; m < 4; m++)
    #pragma unroll
    for (int n = 0; n < 4; n++) {
      int gc = col0 + wc + n * 16 + (lane & 15);
      bool ev = (gc & 1) == 0;
      #pragma unroll
      for (int r = 0; r < 4; r++) {
        int gr = row0 + wr + m * 16 + ((lane >> 4) << 2) + r;  // t
        float v = fmaxf(acc[m][n][r], 0.f);
        float vo = __shfl_xor(v, 1, 64);
        if (ev) {
          long hsi = ((long)b * T_ + gr) * (NH_ * NI_) + head * NI_ + gc;
          unsigned hp = *(const unsigned*)(hs + hsi);
          float o0 = v * b2f((u16)hp);
          float o1 = vo * b2f((u16)(hp >> 16));
          *(unsigned*)(xy + hsi) = (unsigned)f2b(o0) | ((unsigned)f2b(o1) << 16);
        }
      }
    }
}

// ---------- yMLP partials: ymlpp[ks][bt][d] = xy @ dec  (split-K 16) ----------
// grid (2, 8, 16)
__global__ __launch_bounds__(256)
void g_ymlp(const u16* __restrict__ xy, const u16* __restrict__ dect,
            float* __restrict__ ymlpp) {
  __shared__ u16 Als[128 * 32], Bls[128 * 32];
  int ks = blockIdx.z;
  int row0 = blockIdx.y * 128, col0 = blockIdx.x * 128;
  f32x4 acc[4][4];
  gemm128(xy, dect, NH_ * NI_, ks * 1024, ks * 1024 + 1024, row0, col0, Als, Bls, acc);
  EPILOG_SETUP
  float* C = ymlpp + (long)ks * (B_ * T_) * D_;
  #pragma unroll
  for (int m = 0; m < 4; m++)
    #pragma unroll
    for (int n = 0; n < 4; n++) {
      int gc = col0 + wc + n * 16 + (lane & 15);
      #pragma unroll
      for (int r = 0; r < 4; r++) {
        int gr = row0 + wr + m * 16 + ((lane >> 4) << 2) + r;
        C[(long)gr * D_ + gc] = acc[m][n][r];
      }
    }
}

// ---------- h = LN(h + LN(sum of 16 partials)); writes all 3 h layouts ----------
__global__ __launch_bounds__(256)
void k_dln(const float* __restrict__ ymlpp, float* __restrict__ hf,
           u16* __restrict__ hbf, u16* __restrict__ hT) {
  __shared__ float sb[4];
  int bt = blockIdx.x;
  int d = threadIdx.x;
  float acc = 0.f;
  #pragma unroll
  for (int p = 0; p < 16; p++)
    acc += ymlpp[((long)p * (B_ * T_) + bt) * D_ + d];
  float mean = blkSum256(acc, sb) * (1.0f / D_);
  float c = acc - mean;
  float var = blkSum256(c * c, sb) * (1.0f / D_);
  float u = c * rsqrtf(var + EPS_);
  float v2 = hf[(long)bt * D_ + d] + u;
  float m2 = blkSum256(v2, sb) * (1.0f / D_);
  float c2 = v2 - m2;
  float va2 = blkSum256(c2 * c2, sb) * (1.0f / D_);
  float out = c2 * rsqrtf(va2 + EPS_);
  hf[(long)bt * D_ + d] = out;
  hbf[(long)bt * D_ + d] = f2b(out);
  hT[((long)(bt >> 9) * D_ + d) * T_ + (bt & 511)] = f2b(out);
}

// ---------- head ----------
__global__ __launch_bounds__(384)
void k_head(const float* __restrict__ h, const float* __restrict__ W,
            const float* __restrict__ bb, float* __restrict__ out) {
  __shared__ float hr[D_];
  int bt = blockIdx.x;
  int j = threadIdx.x;
  for (int k = j; k < D_; k += 384) hr[k] = h[(long)bt * D_ + k];
  __syncthreads();
  if (j < IN_DIM_) {
    float acc = bb[j];
    for (int d2 = 0; d2 < D_; d2++) acc += hr[d2] * W[(long)d2 * IN_DIM_ + j];
    out[(long)bt * IN_DIM_ + j] = acc;
  }
}

extern "C" void kernel_launch(void* const* d_in, const int* in_sizes, int n_in,
                              void* d_out, int out_size, void* d_ws, size_t ws_size,
                              hipStream_t stream) {
  const float* x    = (const float*)d_in[0];
  const float* in_W = (const float*)d_in[1];
  const float* in_b = (const float*)d_in[2];
  const float* enc  = (const float*)d_in[3];
  const float* encv = (const float*)d_in[4];
  const float* dec  = (const float*)d_in[5];
  const float* hW   = (const float*)d_in[6];
  const float* hb   = (const float*)d_in[7];
  float* out = (float*)d_out;

  char* p = (char*)d_ws;
  auto alloc = [&](size_t bytes) { char* r = p; p += (bytes + 255) & ~(size_t)255; return r; };
  float* cosT  = (float*)alloc((size_t)T_ * (NI_ / 2) * 4);         // 4 MB
  float* sinT  = (float*)alloc((size_t)T_ * (NI_ / 2) * 4);         // 4 MB
  float* hf    = (float*)alloc((size_t)B_ * T_ * D_ * 4);           // 1 MB
  u16*   hbf   = (u16*)  alloc((size_t)B_ * T_ * D_ * 2);           // 0.5 MB
  u16*   hT    = (u16*)  alloc((size_t)B_ * D_ * T_ * 2);           // 0.5 MB
  u16*   enct  = (u16*)  alloc((size_t)NH_ * D_ * NI_ * 2);         // 8 MB
  u16*   encvt = (u16*)  alloc((size_t)NH_ * D_ * NI_ * 2);         // 8 MB
  u16*   dect  = (u16*)  alloc((size_t)NH_ * NI_ * D_ * 2);         // 8 MB
  u16*   hs    = (u16*)  alloc((size_t)B_ * T_ * NH_ * NI_ * 2);    // 32 MB
  u16*   qr    = (u16*)  alloc((size_t)B_ * T_ * NH_ * NI_ * 2);    // 32 MB (reused as xy)
  u16*   scb   = (u16*)  alloc((size_t)B_ * NH_ * T_ * T_ * 2);     // 4 MB
  u16*   ykvb  = (u16*)  alloc((size_t)B_ * NH_ * T_ * D_ * 2);     // 2 MB
  float* pscr  = (float*)alloc((size_t)32 * 1024 * 1024);           // 32 MB shared scratch
  u16*   xy    = qr;

  k_rope_tables<<<dim3(4096), dim3(256), 0, stream>>>(cosT, sinT);
  ktr<<<dim3(NI_ / 64, D_ / 64, NH_), dim3(256), 0, stream>>>(enc, enct, D_, NI_);
  ktr<<<dim3(NI_ / 64, D_ / 64, NH_), dim3(256), 0, stream>>>(encv, encvt, D_, NI_);
  ktr<<<dim3(D_ / 64, (NH_ * NI_) / 64, 1), dim3(256), 0, stream>>>(dec, dect, NH_ * NI_, D_);
  k_input<<<dim3(B_ * T_), dim3(256), 0, stream>>>(x, in_W, in_b, hf, hbf, hT);

  for (int l = 0; l < NL_; l++) {
    g_enc<<<dim3(32, 8, NH_), dim3(256), 0, stream>>>(hbf, enct, cosT, sinT, hs, qr);
    g_scores<<<dim3(4, 4, 32), dim3(256), 0, stream>>>(qr, pscr);
    k_scred<<<dim3(2048), dim3(256), 0, stream>>>(pscr, scb);
    g_ykv<<<dim3(2, 4, 32), dim3(256), 0, stream>>>(scb, hT, pscr);
    k_lnykv<<<dim3(B_ * NH_ * T_), dim3(256), 0, stream>>>(pscr, ykvb);
    g_ysp<<<dim3(32, 4, B_ * NH_), dim3(256), 0, stream>>>(ykvb, encvt, hs, xy);
    g_ymlp<<<dim3(2, 8, 16), dim3(256), 0, stream>>>(xy, dect, pscr);
    k_dln<<<dim3(B_ * T_), dim3(256), 0, stream>>>(pscr, hf, hbf, hT);
  }

  k_head<<<dim3(B_ * T_), dim3(384), 0, stream>>>(hf, hW, hb, out);
}